// Round 3
// baseline (319.184 us; speedup 1.0000x reference)
//
#include <hip/hip_runtime.h>

typedef unsigned short u16;
typedef __attribute__((ext_vector_type(8))) __bf16 bf16x8;
typedef __attribute__((ext_vector_type(4))) float f32x4;
typedef __attribute__((ext_vector_type(4))) unsigned short u16x4;

#define AS1 __attribute__((address_space(1)))
#define AS3 __attribute__((address_space(3)))

// ---- element counts (B=4096, IN=HID=1024) ----
// blob layout (u16 element offsets inside ws blob) -- GEMM inputs only
#define OB_X    0L
#define OB_H    4194304L
#define OB_WI   8388608L
#define OB_WF   10485760L
#define OB_WO   12582912L
#define OB_WXS  14680064L
#define OB_WXG  15728640L
#define OB_WHG  16777216L
#define BLOB_EL 17825792L           // total u16 elements
#define BLOB_BYTES (BLOB_EL * 2)    // 35,651,584

__device__ __forceinline__ float b2f(u16 u) {
    return __uint_as_float(((unsigned)u) << 16);
}
__device__ __forceinline__ u16 f2b(float f) {
    unsigned u = __float_as_uint(f);
    u += 0x7fffu + ((u >> 16) & 1u);   // round-to-nearest-even
    return (u16)(u >> 16);
}

__device__ __forceinline__ void storeY(float* p, float v) { *p = v; }
__device__ __forceinline__ void storeY(u16* p, float v) { *p = f2b(v); }
__device__ __forceinline__ f32x4 loadY4(const float* p) { return *(const f32x4*)p; }
__device__ __forceinline__ f32x4 loadY4(const u16* p) {
    u16x4 v = *(const u16x4*)p;
    f32x4 r;
    r.x = b2f(v.x); r.y = b2f(v.y); r.z = b2f(v.z); r.w = b2f(v.w);
    return r;
}
// flag-steered mixed-dtype vector load (fl==1: bf16, fl==0: f32)
__device__ __forceinline__ f32x4 loadMix4(const void* p, long i, unsigned fl) {
    if (fl) {
        u16x4 v = *(const u16x4*)((const u16*)p + i);
        f32x4 r;
        r.x = b2f(v.x); r.y = b2f(v.y); r.z = b2f(v.z); r.w = b2f(v.w);
        return r;
    }
    return *(const f32x4*)((const float*)p + i);
}

// ---------------- per-tensor dtype detection ----------------
// Inspect low u16 of first 256 u32 words. bf16 data: low u16 is a real bf16
// value (exp in [100,150] essentially always). f32 data: low u16 is mantissa
// bits (~20% land in that exponent window). Threshold at 128/256.
__global__ void detect_dtype(
    const unsigned* __restrict__ p0,  const unsigned* __restrict__ p1,
    const unsigned* __restrict__ p2,  const unsigned* __restrict__ p3,
    const unsigned* __restrict__ p4,  const unsigned* __restrict__ p5,
    const unsigned* __restrict__ p6,  const unsigned* __restrict__ p7,
    const unsigned* __restrict__ p8,  const unsigned* __restrict__ p9,
    const unsigned* __restrict__ p10, const unsigned* __restrict__ p11,
    const unsigned* __restrict__ p12, const unsigned* __restrict__ p13,
    const unsigned* __restrict__ p14, unsigned* __restrict__ flags)
{
    const unsigned* ptrs[15] = {p0,p1,p2,p3,p4,p5,p6,p7,p8,p9,p10,p11,p12,p13,p14};
    __shared__ int cnt;
    if (threadIdx.x == 0) cnt = 0;
    __syncthreads();
    unsigned u = ptrs[blockIdx.x][threadIdx.x];   // smallest tensor: 1024 elems >= 256 words either dtype
    unsigned ex = ((u & 0xffffu) >> 7) & 0xffu;
    int sane = (ex >= 100u && ex <= 150u) ? 1 : 0;
    atomicAdd(&cnt, sane);
    __syncthreads();
    if (threadIdx.x == 0) flags[blockIdx.x] = (cnt >= 128) ? 1u : 0u;  // 1 = bf16
}

// ---------------- build bf16 blob (convert f32 or copy bf16, per flag) ----------------
__global__ __launch_bounds__(256) void convert_all(
    const unsigned* __restrict__ flags,
    const void* __restrict__ x, const void* __restrict__ h,
    const void* __restrict__ Wi, const void* __restrict__ Wf,
    const void* __restrict__ Wo, const void* __restrict__ Wxs,
    const void* __restrict__ Wxg, const void* __restrict__ Whg,
    u16* __restrict__ blob)
{
    long e = ((long)blockIdx.x * 256 + threadIdx.x) * 8;
    const void* src; long off; int fi;
    if      (e < OB_H)   { src = x;   off = e;          fi = 0; }
    else if (e < OB_WI)  { src = h;   off = e - OB_H;   fi = 1; }
    else if (e < OB_WF)  { src = Wi;  off = e - OB_WI;  fi = 3; }
    else if (e < OB_WO)  { src = Wf;  off = e - OB_WF;  fi = 5; }
    else if (e < OB_WXS) { src = Wo;  off = e - OB_WO;  fi = 7; }
    else if (e < OB_WXG) { src = Wxs; off = e - OB_WXS; fi = 9; }
    else if (e < OB_WHG) { src = Wxg; off = e - OB_WXG; fi = 11; }
    else                 { src = Whg; off = e - OB_WHG; fi = 13; }
    if (flags[fi]) {                    // already bf16: straight copy
        *(u16x4*)(blob + e)     = *(const u16x4*)((const u16*)src + off);
        *(u16x4*)(blob + e + 4) = *(const u16x4*)((const u16*)src + off + 4);
    } else {                            // f32: convert
        f32x4 v0 = *(const f32x4*)((const float*)src + off);
        f32x4 v1 = *(const f32x4*)((const float*)src + off + 4);
        u16x4 o0, o1;
        o0.x = f2b(v0.x); o0.y = f2b(v0.y); o0.z = f2b(v0.z); o0.w = f2b(v0.w);
        o1.x = f2b(v1.x); o1.y = f2b(v1.y); o1.z = f2b(v1.z); o1.w = f2b(v1.w);
        *(u16x4*)(blob + e) = o0;
        *(u16x4*)(blob + e + 4) = o1;
    }
}

// ---------------- fused GEMM: Y[4096,5120] = [x|h] @ W_all^T ----------------
//   n seg 0..2: Wi/Wf/Wo (ld 2048, K=2048; cols 0:1024 hit x, 1024:2048 hit h)
//   n seg 3:    k<1024 Wxg, k>=1024 Whg (ld 1024, K=2048)
//   n seg 4:    Wxs, K=1024 (x only)
// m97 structure: 128x128 tile, BK=64, 4 waves of 64x64 (4x4 mfma_f32_16x16x32_bf16),
// global_load_lds width 16, two-barrier K-loop. All inputs from bf16 blob.
template <typename YT>
__global__ __launch_bounds__(256) void srulstm_gemm(
    const u16* __restrict__ blob, YT* __restrict__ Y)
{
    __shared__ __align__(16) u16 As[128 * 64];
    __shared__ __align__(16) u16 Bs[128 * 64];

    const u16* x   = blob + OB_X;
    const u16* h   = blob + OB_H;
    const u16* Wi  = blob + OB_WI;
    const u16* Wf  = blob + OB_WF;
    const u16* Wo  = blob + OB_WO;
    const u16* Wxs = blob + OB_WXS;
    const u16* Wxg = blob + OB_WXG;
    const u16* Whg = blob + OB_WHG;

    const int t = threadIdx.x;
    const int n0 = blockIdx.x * 128;   // 40 tiles
    const int m0 = blockIdx.y * 128;   // 32 tiles
    const int seg = n0 >> 10;
    const int row0 = n0 & 1023;

    const u16* bLo; const u16* bHi; int bLd; int kLim;
    if (seg == 0)      { bLo = Wi  + row0 * 2048; bHi = bLo + 1024;        bLd = 2048; kLim = 2048; }
    else if (seg == 1) { bLo = Wf  + row0 * 2048; bHi = bLo + 1024;        bLd = 2048; kLim = 2048; }
    else if (seg == 2) { bLo = Wo  + row0 * 2048; bHi = bLo + 1024;        bLd = 2048; kLim = 2048; }
    else if (seg == 3) { bLo = Wxg + row0 * 1024; bHi = Whg + row0 * 1024; bLd = 1024; kLim = 2048; }
    else               { bLo = Wxs + row0 * 1024; bHi = bLo;               bLd = 1024; kLim = 1024; }

    const u16* aLo = x + m0 * 1024;
    const u16* aHi = h + m0 * 1024;

    const int lane = t & 63;
    const int wave = t >> 6;
    const int wm = (wave >> 1) << 6;
    const int wn = (wave & 1) << 6;
    const int fr = lane & 15;
    const int fq = lane >> 4;
    const int fk = fq << 3;

    f32x4 acc[4][4] = {};

    const int er = t >> 3;
    const int ec = (t & 7) << 3;

    for (int k0 = 0; k0 < kLim; k0 += 64) {
        const int kc = k0 & 1023;
        const u16* aSrc = ((k0 < 1024) ? aLo : aHi) + kc;
        const u16* bSrc = ((k0 < 1024) ? bLo : bHi) + kc;
#pragma unroll
        for (int it = 0; it < 4; ++it) {
            const int row = it * 32 + er;
            __builtin_amdgcn_global_load_lds(
                (AS1 void*)(aSrc + row * 1024 + ec),
                (AS3 void*)(As + (it * 256 + t) * 8), 16, 0, 0);
        }
#pragma unroll
        for (int it = 0; it < 4; ++it) {
            const int row = it * 32 + er;
            __builtin_amdgcn_global_load_lds(
                (AS1 void*)(bSrc + row * bLd + ec),
                (AS3 void*)(Bs + (it * 256 + t) * 8), 16, 0, 0);
        }
        __syncthreads();
#pragma unroll
        for (int kk = 0; kk < 64; kk += 32) {
            bf16x8 a[4], b[4];
#pragma unroll
            for (int mi = 0; mi < 4; ++mi)
                a[mi] = *(const bf16x8*)(As + (wm + mi * 16 + fr) * 64 + kk + fk);
#pragma unroll
            for (int ni = 0; ni < 4; ++ni)
                b[ni] = *(const bf16x8*)(Bs + (wn + ni * 16 + fr) * 64 + kk + fk);
#pragma unroll
            for (int mi = 0; mi < 4; ++mi)
#pragma unroll
                for (int ni = 0; ni < 4; ++ni)
                    acc[mi][ni] = __builtin_amdgcn_mfma_f32_16x16x32_bf16(
                        a[mi], b[ni], acc[mi][ni], 0, 0, 0);
        }
        __syncthreads();
    }

    // C/D layout (m89): lane holds D[m=(lane>>4)*4+r][n=lane&15]
    const int orow = m0 + wm + fq * 4;
    const int ocol = n0 + wn + fr;
#pragma unroll
    for (int mi = 0; mi < 4; ++mi)
#pragma unroll
        for (int ni = 0; ni < 4; ++ni) {
            YT* yp = Y + (long)(orow + mi * 16) * 5120 + (ocol + ni * 16);
#pragma unroll
            for (int r = 0; r < 4; ++r)
                storeY(yp + (long)r * 5120, acc[mi][ni][r]);
        }
}

// ---------------- elementwise epilogue (f32 outputs) ----------------
template <typename YT>
__global__ __launch_bounds__(256) void srulstm_epilogue(
    const unsigned* __restrict__ flags,
    const YT* __restrict__ Y, const void* __restrict__ c_prev,
    const void* __restrict__ bi, const void* __restrict__ bfv,
    const void* __restrict__ bo, const void* __restrict__ bxs,
    const void* __restrict__ bxg, const void* __restrict__ bhg,
    float* __restrict__ out)
{
    const int gid = blockIdx.x * 256 + threadIdx.x;
    const int b = gid >> 8;
    const int j = (gid & 255) << 2;
    const long yb = (long)b * 5120 + j;

    f32x4 zi = loadY4(Y + yb);
    f32x4 zf = loadY4(Y + yb + 1024);
    f32x4 zo = loadY4(Y + yb + 2048);
    f32x4 zc = loadY4(Y + yb + 3072);
    f32x4 zs = loadY4(Y + yb + 4096);

    f32x4 cp  = loadMix4(c_prev, (long)b * 1024 + j, flags[2]);
    f32x4 vbi = loadMix4(bi,  j, flags[4]);
    f32x4 vbf = loadMix4(bfv, j, flags[6]);
    f32x4 vbo = loadMix4(bo,  j, flags[8]);
    f32x4 vbs = loadMix4(bxs, j, flags[10]);
    f32x4 vbg = loadMix4(bxg, j, flags[12]);
    f32x4 vbh = loadMix4(bhg, j, flags[14]);

    f32x4 ho, co;
#pragma unroll
    for (int r = 0; r < 4; ++r) {
        float i_t = 1.f / (1.f + __expf(-(zi[r] + vbi[r])));
        float f_t = 1.f / (1.f + __expf(-(zf[r] + vbf[r])));
        float o_t = 1.f / (1.f + __expf(-(zo[r] + vbo[r])));
        float s_t = zs[r] + vbs[r];
        float cand = zc[r] + vbg[r] + vbh[r];
        float g_t = tanhf(s_t * cand);
        float c_t = f_t * cp[r] + i_t * g_t;
        float h_t = o_t * tanhf(c_t);
        ho[r] = h_t;
        co[r] = c_t;
    }
    *(f32x4*)(out + (long)b * 1024 + j) = ho;                 // h_t  [f32]
    *(f32x4*)(out + 4194304L + (long)b * 1024 + j) = co;      // c_t  [f32]
}

extern "C" void kernel_launch(void* const* d_in, const int* in_sizes, int n_in,
                              void* d_out, int out_size, void* d_ws, size_t ws_size,
                              hipStream_t stream)
{
    unsigned* flags = (unsigned*)d_ws;                       // 64-byte header (15 flags)
    u16* blob = (u16*)((char*)d_ws + 64);
    char* yBase = (char*)d_ws + 64 + BLOB_BYTES;
    float* out = (float*)d_out;

    dim3 gg(40, 32), gb(256);
    dim3 eg(4096), eb(256);
    const long convBlocks = BLOB_EL / 8 / 256;               // 8704

    detect_dtype<<<15, 256, 0, stream>>>(
        (const unsigned*)d_in[0],  (const unsigned*)d_in[1],  (const unsigned*)d_in[2],
        (const unsigned*)d_in[3],  (const unsigned*)d_in[4],  (const unsigned*)d_in[5],
        (const unsigned*)d_in[6],  (const unsigned*)d_in[7],  (const unsigned*)d_in[8],
        (const unsigned*)d_in[9],  (const unsigned*)d_in[10], (const unsigned*)d_in[11],
        (const unsigned*)d_in[12], (const unsigned*)d_in[13], (const unsigned*)d_in[14],
        flags);
    convert_all<<<dim3(convBlocks), dim3(256), 0, stream>>>(
        flags, d_in[0], d_in[1], d_in[3], d_in[5], d_in[7], d_in[9], d_in[11], d_in[13],
        blob);

    const size_t needF32 = 64 + (size_t)BLOB_BYTES + (size_t)4096 * 5120 * 4;
    if (ws_size >= needF32) {
        float* Y = (float*)yBase;
        srulstm_gemm<float><<<gg, gb, 0, stream>>>(blob, Y);
        srulstm_epilogue<float><<<eg, eb, 0, stream>>>(
            flags, Y, d_in[2], d_in[4], d_in[6], d_in[8], d_in[10], d_in[12], d_in[14], out);
    } else {
        u16* Y = (u16*)yBase;
        srulstm_gemm<u16><<<gg, gb, 0, stream>>>(blob, Y);
        srulstm_epilogue<u16><<<eg, eb, 0, stream>>>(
            flags, Y, d_in[2], d_in[4], d_in[6], d_in[8], d_in[10], d_in[12], d_in[14], out);
    }
}

// Round 4
// 285.621 us; speedup vs baseline: 1.1175x; 1.1175x over previous
//
#include <hip/hip_runtime.h>

typedef unsigned short u16;
typedef __attribute__((ext_vector_type(8))) __bf16 bf16x8;
typedef __attribute__((ext_vector_type(4))) float f32x4;
typedef __attribute__((ext_vector_type(4))) unsigned short u16x4;

#define AS1 __attribute__((address_space(1)))
#define AS3 __attribute__((address_space(3)))

// blob layout (u16 element offsets inside ws blob) -- GEMM inputs only
#define OB_X    0L
#define OB_H    4194304L
#define OB_WI   8388608L
#define OB_WF   10485760L
#define OB_WO   12582912L
#define OB_WXS  14680064L
#define OB_WXG  15728640L
#define OB_WHG  16777216L
#define BLOB_EL 17825792L
#define BLOB_BYTES (BLOB_EL * 2)

__device__ __forceinline__ float b2f(u16 u) {
    return __uint_as_float(((unsigned)u) << 16);
}
__device__ __forceinline__ u16 f2b(float f) {
    unsigned u = __float_as_uint(f);
    u += 0x7fffu + ((u >> 16) & 1u);   // round-to-nearest-even
    return (u16)(u >> 16);
}

__device__ __forceinline__ void storeY(float* p, float v) { *p = v; }
__device__ __forceinline__ void storeY(u16* p, float v) { *p = f2b(v); }
__device__ __forceinline__ f32x4 loadY4(const float* p) { return *(const f32x4*)p; }
__device__ __forceinline__ f32x4 loadY4(const u16* p) {
    u16x4 v = *(const u16x4*)p;
    f32x4 r;
    r.x = b2f(v.x); r.y = b2f(v.y); r.z = b2f(v.z); r.w = b2f(v.w);
    return r;
}
__device__ __forceinline__ f32x4 loadMix4(const void* p, long i, unsigned fl) {
    if (fl) {
        u16x4 v = *(const u16x4*)((const u16*)p + i);
        f32x4 r;
        r.x = b2f(v.x); r.y = b2f(v.y); r.z = b2f(v.z); r.w = b2f(v.w);
        return r;
    }
    return *(const f32x4*)((const float*)p + i);
}

// ---------------- per-tensor dtype detection ----------------
__global__ void detect_dtype(
    const unsigned* __restrict__ p0,  const unsigned* __restrict__ p1,
    const unsigned* __restrict__ p2,  const unsigned* __restrict__ p3,
    const unsigned* __restrict__ p4,  const unsigned* __restrict__ p5,
    const unsigned* __restrict__ p6,  const unsigned* __restrict__ p7,
    const unsigned* __restrict__ p8,  const unsigned* __restrict__ p9,
    const unsigned* __restrict__ p10, const unsigned* __restrict__ p11,
    const unsigned* __restrict__ p12, const unsigned* __restrict__ p13,
    const unsigned* __restrict__ p14, unsigned* __restrict__ flags)
{
    const unsigned* ptrs[15] = {p0,p1,p2,p3,p4,p5,p6,p7,p8,p9,p10,p11,p12,p13,p14};
    __shared__ int cnt;
    if (threadIdx.x == 0) cnt = 0;
    __syncthreads();
    unsigned u = ptrs[blockIdx.x][threadIdx.x];
    unsigned ex = ((u & 0xffffu) >> 7) & 0xffu;
    int sane = (ex >= 100u && ex <= 150u) ? 1 : 0;
    atomicAdd(&cnt, sane);
    __syncthreads();
    if (threadIdx.x == 0) flags[blockIdx.x] = (cnt >= 128) ? 1u : 0u;  // 1 = bf16
}

// ---------------- build bf16 blob ----------------
__global__ __launch_bounds__(256) void convert_all(
    const unsigned* __restrict__ flags,
    const void* __restrict__ x, const void* __restrict__ h,
    const void* __restrict__ Wi, const void* __restrict__ Wf,
    const void* __restrict__ Wo, const void* __restrict__ Wxs,
    const void* __restrict__ Wxg, const void* __restrict__ Whg,
    u16* __restrict__ blob)
{
    long e = ((long)blockIdx.x * 256 + threadIdx.x) * 8;
    const void* src; long off; int fi;
    if      (e < OB_H)   { src = x;   off = e;          fi = 0; }
    else if (e < OB_WI)  { src = h;   off = e - OB_H;   fi = 1; }
    else if (e < OB_WF)  { src = Wi;  off = e - OB_WI;  fi = 3; }
    else if (e < OB_WO)  { src = Wf;  off = e - OB_WF;  fi = 5; }
    else if (e < OB_WXS) { src = Wo;  off = e - OB_WO;  fi = 7; }
    else if (e < OB_WXG) { src = Wxs; off = e - OB_WXS; fi = 9; }
    else if (e < OB_WHG) { src = Wxg; off = e - OB_WXG; fi = 11; }
    else                 { src = Whg; off = e - OB_WHG; fi = 13; }
    if (flags[fi]) {
        *(u16x4*)(blob + e)     = *(const u16x4*)((const u16*)src + off);
        *(u16x4*)(blob + e + 4) = *(const u16x4*)((const u16*)src + off + 4);
    } else {
        f32x4 v0 = *(const f32x4*)((const float*)src + off);
        f32x4 v1 = *(const f32x4*)((const float*)src + off + 4);
        u16x4 o0, o1;
        o0.x = f2b(v0.x); o0.y = f2b(v0.y); o0.z = f2b(v0.z); o0.w = f2b(v0.w);
        o1.x = f2b(v1.x); o1.y = f2b(v1.y); o1.z = f2b(v1.z); o1.w = f2b(v1.w);
        *(u16x4*)(blob + e) = o0;
        *(u16x4*)(blob + e + 4) = o1;
    }
}

// ---------------- fused GEMM: Y[4096,5120] = [x|h] @ W_all^T ----------------
// m97 structure + XOR-swizzled LDS layout to kill ds_read_b128 bank conflicts:
// LDS row r (128B), 16B-granule slot j holds global granule (j ^ (r&7)).
// Staging picks the swizzled SOURCE granule (dst must stay lane-contiguous for
// global_load_lds); ds_read addresses granule (g ^ (r&7)). After swizzle each
// quad-group's 16 lanes spread over all 32 banks, 2 lanes/bank (free, m136).
template <typename YT>
__global__ __launch_bounds__(256) void srulstm_gemm(
    const u16* __restrict__ blob, YT* __restrict__ Y)
{
    __shared__ __align__(16) u16 As[128 * 64];
    __shared__ __align__(16) u16 Bs[128 * 64];

    const u16* x   = blob + OB_X;
    const u16* h   = blob + OB_H;
    const u16* Wi  = blob + OB_WI;
    const u16* Wf  = blob + OB_WF;
    const u16* Wo  = blob + OB_WO;
    const u16* Wxs = blob + OB_WXS;
    const u16* Wxg = blob + OB_WXG;
    const u16* Whg = blob + OB_WHG;

    const int t = threadIdx.x;
    const int n0 = blockIdx.x * 128;   // 40 n-tiles
    const int m0 = blockIdx.y * 128;   // 32 m-tiles
    const int seg = n0 >> 10;
    const int row0 = n0 & 1023;

    const u16* bLo; const u16* bHi; int bLd; int kLim;
    if (seg == 0)      { bLo = Wi  + row0 * 2048; bHi = bLo + 1024;        bLd = 2048; kLim = 2048; }
    else if (seg == 1) { bLo = Wf  + row0 * 2048; bHi = bLo + 1024;        bLd = 2048; kLim = 2048; }
    else if (seg == 2) { bLo = Wo  + row0 * 2048; bHi = bLo + 1024;        bLd = 2048; kLim = 2048; }
    else if (seg == 3) { bLo = Wxg + row0 * 1024; bHi = Whg + row0 * 1024; bLd = 1024; kLim = 2048; }
    else               { bLo = Wxs + row0 * 1024; bHi = bLo;               bLd = 1024; kLim = 1024; }

    const u16* aLo = x + m0 * 1024;
    const u16* aHi = h + m0 * 1024;

    const int lane = t & 63;
    const int wave = t >> 6;
    const int wm = (wave >> 1) << 6;
    const int wn = (wave & 1) << 6;
    const int fr = lane & 15;
    const int fq = lane >> 4;
    const int r7 = fr & 7;             // (frag row) & 7 — swizzle key for reads

    f32x4 acc[4][4] = {};

    const int er = t >> 3;             // staging row within 32-row chunk
    // swizzled source granule: slot (t&7) in row er holds global granule (t&7)^(er&7)
    const int gsw = (((t & 7) ^ (er & 7)) << 3);   // element offset

    for (int k0 = 0; k0 < kLim; k0 += 64) {
        const int kc = k0 & 1023;
        const u16* aSrc = ((k0 < 1024) ? aLo : aHi) + kc;
        const u16* bSrc = ((k0 < 1024) ? bLo : bHi) + kc;
#pragma unroll
        for (int it = 0; it < 4; ++it) {
            const int row = it * 32 + er;
            __builtin_amdgcn_global_load_lds(
                (AS1 void*)(aSrc + row * 1024 + gsw),
                (AS3 void*)(As + (it * 256 + t) * 8), 16, 0, 0);
        }
#pragma unroll
        for (int it = 0; it < 4; ++it) {
            const int row = it * 32 + er;
            __builtin_amdgcn_global_load_lds(
                (AS1 void*)(bSrc + row * bLd + gsw),
                (AS3 void*)(Bs + (it * 256 + t) * 8), 16, 0, 0);
        }
        __syncthreads();
#pragma unroll
        for (int kk = 0; kk < 64; kk += 32) {
            // wanted granule g = kk/8 + fq; read LDS granule (g ^ r7)
            const int sw = ((((kk >> 3) + fq) ^ r7) << 3);
            bf16x8 a[4], b[4];
#pragma unroll
            for (int mi = 0; mi < 4; ++mi)
                a[mi] = *(const bf16x8*)(As + (wm + mi * 16 + fr) * 64 + sw);
#pragma unroll
            for (int ni = 0; ni < 4; ++ni)
                b[ni] = *(const bf16x8*)(Bs + (wn + ni * 16 + fr) * 64 + sw);
#pragma unroll
            for (int mi = 0; mi < 4; ++mi)
#pragma unroll
                for (int ni = 0; ni < 4; ++ni)
                    acc[mi][ni] = __builtin_amdgcn_mfma_f32_16x16x32_bf16(
                        a[mi], b[ni], acc[mi][ni], 0, 0, 0);
        }
        __syncthreads();
    }

    // C/D layout (m89): lane holds D[m=(lane>>4)*4+r][n=lane&15]
    const int orow = m0 + wm + (fq << 2);
    const int ocol = n0 + wn + fr;
#pragma unroll
    for (int mi = 0; mi < 4; ++mi)
#pragma unroll
        for (int ni = 0; ni < 4; ++ni) {
            YT* yp = Y + (long)(orow + mi * 16) * 5120 + (ocol + ni * 16);
#pragma unroll
            for (int r = 0; r < 4; ++r)
                storeY(yp + (long)r * 5120, acc[mi][ni][r]);
        }
}

// ---------------- elementwise epilogue (f32 outputs) ----------------
template <typename YT>
__global__ __launch_bounds__(256) void srulstm_epilogue(
    const unsigned* __restrict__ flags,
    const YT* __restrict__ Y, const void* __restrict__ c_prev,
    const void* __restrict__ bi, const void* __restrict__ bfv,
    const void* __restrict__ bo, const void* __restrict__ bxs,
    const void* __restrict__ bxg, const void* __restrict__ bhg,
    float* __restrict__ out)
{
    const int gid = blockIdx.x * 256 + threadIdx.x;
    const int b = gid >> 8;
    const int j = (gid & 255) << 2;
    const long yb = (long)b * 5120 + j;

    f32x4 zi = loadY4(Y + yb);
    f32x4 zf = loadY4(Y + yb + 1024);
    f32x4 zo = loadY4(Y + yb + 2048);
    f32x4 zc = loadY4(Y + yb + 3072);
    f32x4 zs = loadY4(Y + yb + 4096);

    f32x4 cp  = loadMix4(c_prev, (long)b * 1024 + j, flags[2]);
    f32x4 vbi = loadMix4(bi,  j, flags[4]);
    f32x4 vbf = loadMix4(bfv, j, flags[6]);
    f32x4 vbo = loadMix4(bo,  j, flags[8]);
    f32x4 vbs = loadMix4(bxs, j, flags[10]);
    f32x4 vbg = loadMix4(bxg, j, flags[12]);
    f32x4 vbh = loadMix4(bhg, j, flags[14]);

    f32x4 ho, co;
#pragma unroll
    for (int r = 0; r < 4; ++r) {
        float i_t = 1.f / (1.f + __expf(-(zi[r] + vbi[r])));
        float f_t = 1.f / (1.f + __expf(-(zf[r] + vbf[r])));
        float o_t = 1.f / (1.f + __expf(-(zo[r] + vbo[r])));
        float s_t = zs[r] + vbs[r];
        float cand = zc[r] + vbg[r] + vbh[r];
        float g_t = tanhf(s_t * cand);
        float c_t = f_t * cp[r] + i_t * g_t;
        float h_t = o_t * tanhf(c_t);
        ho[r] = h_t;
        co[r] = c_t;
    }
    *(f32x4*)(out + (long)b * 1024 + j) = ho;                 // h_t  [f32]
    *(f32x4*)(out + 4194304L + (long)b * 1024 + j) = co;      // c_t  [f32]
}

extern "C" void kernel_launch(void* const* d_in, const int* in_sizes, int n_in,
                              void* d_out, int out_size, void* d_ws, size_t ws_size,
                              hipStream_t stream)
{
    unsigned* flags = (unsigned*)d_ws;                       // 64-byte header (15 flags)
    u16* blob = (u16*)((char*)d_ws + 64);
    char* yBase = (char*)d_ws + 64 + BLOB_BYTES;
    float* out = (float*)d_out;

    dim3 gg(40, 32), gb(256);
    dim3 eg(4096), eb(256);
    const long convBlocks = BLOB_EL / 8 / 256;               // 8704

    detect_dtype<<<15, 256, 0, stream>>>(
        (const unsigned*)d_in[0],  (const unsigned*)d_in[1],  (const unsigned*)d_in[2],
        (const unsigned*)d_in[3],  (const unsigned*)d_in[4],  (const unsigned*)d_in[5],
        (const unsigned*)d_in[6],  (const unsigned*)d_in[7],  (const unsigned*)d_in[8],
        (const unsigned*)d_in[9],  (const unsigned*)d_in[10], (const unsigned*)d_in[11],
        (const unsigned*)d_in[12], (const unsigned*)d_in[13], (const unsigned*)d_in[14],
        flags);
    convert_all<<<dim3(convBlocks), dim3(256), 0, stream>>>(
        flags, d_in[0], d_in[1], d_in[3], d_in[5], d_in[7], d_in[9], d_in[11], d_in[13],
        blob);

    const size_t needF32 = 64 + (size_t)BLOB_BYTES + (size_t)4096 * 5120 * 4;
    if (ws_size >= needF32) {
        float* Y = (float*)yBase;
        srulstm_gemm<float><<<gg, gb, 0, stream>>>(blob, Y);
        srulstm_epilogue<float><<<eg, eb, 0, stream>>>(
            flags, Y, d_in[2], d_in[4], d_in[6], d_in[8], d_in[10], d_in[12], d_in[14], out);
    } else {
        u16* Y = (u16*)yBase;
        srulstm_gemm<u16><<<gg, gb, 0, stream>>>(blob, Y);
        srulstm_epilogue<u16><<<eg, eb, 0, stream>>>(
            flags, Y, d_in[2], d_in[4], d_in[6], d_in[8], d_in[10], d_in[12], d_in[14], out);
    }
}

// Round 5
// 248.462 us; speedup vs baseline: 1.2846x; 1.1496x over previous
//
#include <hip/hip_runtime.h>

typedef unsigned short u16;
typedef __attribute__((ext_vector_type(8))) __bf16 bf16x8;
typedef __attribute__((ext_vector_type(4))) float f32x4;
typedef __attribute__((ext_vector_type(4))) unsigned short u16x4;

#define AS1 __attribute__((address_space(1)))
#define AS3 __attribute__((address_space(3)))

// blob layout (u16 element offsets inside ws blob) -- GEMM inputs only
#define OB_X    0L
#define OB_H    4194304L
#define OB_WI   8388608L
#define OB_WF   10485760L
#define OB_WO   12582912L
#define OB_WXS  14680064L
#define OB_WXG  15728640L
#define OB_WHG  16777216L
#define BLOB_EL 17825792L
#define BLOB_BYTES (BLOB_EL * 2)

__device__ __forceinline__ float b2f(u16 u) {
    return __uint_as_float(((unsigned)u) << 16);
}
__device__ __forceinline__ u16 f2b(float f) {
    unsigned u = __float_as_uint(f);
    u += 0x7fffu + ((u >> 16) & 1u);   // round-to-nearest-even
    return (u16)(u >> 16);
}
__device__ __forceinline__ f32x4 loadY4(const u16* p) {
    u16x4 v = *(const u16x4*)p;
    f32x4 r;
    r.x = b2f(v.x); r.y = b2f(v.y); r.z = b2f(v.z); r.w = b2f(v.w);
    return r;
}

// ---------------- f32 -> bf16 blob build (inputs are f32; verified r3/r4) ----------------
__global__ __launch_bounds__(256) void convert_all(
    const float* __restrict__ x, const float* __restrict__ h,
    const float* __restrict__ Wi, const float* __restrict__ Wf,
    const float* __restrict__ Wo, const float* __restrict__ Wxs,
    const float* __restrict__ Wxg, const float* __restrict__ Whg,
    u16* __restrict__ blob)
{
    long e = ((long)blockIdx.x * 256 + threadIdx.x) * 8;
    const float* src; long off;
    if      (e < OB_H)   { src = x;   off = e; }
    else if (e < OB_WI)  { src = h;   off = e - OB_H; }
    else if (e < OB_WF)  { src = Wi;  off = e - OB_WI; }
    else if (e < OB_WO)  { src = Wf;  off = e - OB_WF; }
    else if (e < OB_WXS) { src = Wo;  off = e - OB_WO; }
    else if (e < OB_WXG) { src = Wxs; off = e - OB_WXS; }
    else if (e < OB_WHG) { src = Wxg; off = e - OB_WXG; }
    else                 { src = Whg; off = e - OB_WHG; }
    f32x4 v0 = *(const f32x4*)(src + off);
    f32x4 v1 = *(const f32x4*)(src + off + 4);
    u16x4 o0, o1;
    o0.x = f2b(v0.x); o0.y = f2b(v0.y); o0.z = f2b(v0.z); o0.w = f2b(v0.w);
    o1.x = f2b(v1.x); o1.y = f2b(v1.y); o1.z = f2b(v1.z); o1.w = f2b(v1.w);
    *(u16x4*)(blob + e) = o0;
    *(u16x4*)(blob + e + 4) = o1;
}

// ---------------- fused GEMM: Y[4096,5120](bf16) = [x|h] @ W_all^T ----------------
// m97 structure (128x128 tile, BK=64, 4 waves of 64x64, global_load_lds w16)
// + XOR-swizzled LDS (r4: bank conflicts 2.8e7 -> 0).
// LDS row r, 16B-granule slot j holds global granule (j ^ (r&7)); ds_read
// addresses granule (g ^ (r&7)) -> each quad-group spans all 32 banks.
__global__ __launch_bounds__(256, 3) void srulstm_gemm(
    const u16* __restrict__ blob, u16* __restrict__ Y)
{
    __shared__ __align__(16) u16 As[128 * 64];
    __shared__ __align__(16) u16 Bs[128 * 64];

    const u16* x   = blob + OB_X;
    const u16* h   = blob + OB_H;
    const u16* Wi  = blob + OB_WI;
    const u16* Wf  = blob + OB_WF;
    const u16* Wo  = blob + OB_WO;
    const u16* Wxs = blob + OB_WXS;
    const u16* Wxg = blob + OB_WXG;
    const u16* Whg = blob + OB_WHG;

    const int t = threadIdx.x;
    const int n0 = blockIdx.x * 128;   // 40 n-tiles
    const int m0 = blockIdx.y * 128;   // 32 m-tiles
    const int seg = n0 >> 10;
    const int row0 = n0 & 1023;

    const u16* bLo; const u16* bHi; int bLd; int kLim;
    if (seg == 0)      { bLo = Wi  + row0 * 2048; bHi = bLo + 1024;        bLd = 2048; kLim = 2048; }
    else if (seg == 1) { bLo = Wf  + row0 * 2048; bHi = bLo + 1024;        bLd = 2048; kLim = 2048; }
    else if (seg == 2) { bLo = Wo  + row0 * 2048; bHi = bLo + 1024;        bLd = 2048; kLim = 2048; }
    else if (seg == 3) { bLo = Wxg + row0 * 1024; bHi = Whg + row0 * 1024; bLd = 1024; kLim = 2048; }
    else               { bLo = Wxs + row0 * 1024; bHi = bLo;               bLd = 1024; kLim = 1024; }

    const u16* aLo = x + m0 * 1024;
    const u16* aHi = h + m0 * 1024;

    const int lane = t & 63;
    const int wave = t >> 6;
    const int wm = (wave >> 1) << 6;
    const int wn = (wave & 1) << 6;
    const int fr = lane & 15;
    const int fq = lane >> 4;
    const int r7 = fr & 7;             // swizzle key for fragment reads

    f32x4 acc[4][4] = {};

    const int er = t >> 3;             // staging row within 32-row chunk
    const int gsw = (((t & 7) ^ (er & 7)) << 3);   // swizzled source granule offset

    for (int k0 = 0; k0 < kLim; k0 += 64) {
        const int kc = k0 & 1023;
        const u16* aSrc = ((k0 < 1024) ? aLo : aHi) + kc;
        const u16* bSrc = ((k0 < 1024) ? bLo : bHi) + kc;
#pragma unroll
        for (int it = 0; it < 4; ++it) {
            const int row = it * 32 + er;
            __builtin_amdgcn_global_load_lds(
                (AS1 void*)(aSrc + row * 1024 + gsw),
                (AS3 void*)(As + (it * 256 + t) * 8), 16, 0, 0);
        }
#pragma unroll
        for (int it = 0; it < 4; ++it) {
            const int row = it * 32 + er;
            __builtin_amdgcn_global_load_lds(
                (AS1 void*)(bSrc + row * bLd + gsw),
                (AS3 void*)(Bs + (it * 256 + t) * 8), 16, 0, 0);
        }
        __syncthreads();
#pragma unroll
        for (int kk = 0; kk < 64; kk += 32) {
            const int sw = ((((kk >> 3) + fq) ^ r7) << 3);
            bf16x8 a[4], b[4];
#pragma unroll
            for (int mi = 0; mi < 4; ++mi)
                a[mi] = *(const bf16x8*)(As + (wm + mi * 16 + fr) * 64 + sw);
#pragma unroll
            for (int ni = 0; ni < 4; ++ni)
                b[ni] = *(const bf16x8*)(Bs + (wn + ni * 16 + fr) * 64 + sw);
#pragma unroll
            for (int mi = 0; mi < 4; ++mi)
#pragma unroll
                for (int ni = 0; ni < 4; ++ni)
                    acc[mi][ni] = __builtin_amdgcn_mfma_f32_16x16x32_bf16(
                        a[mi], b[ni], acc[mi][ni], 0, 0, 0);
        }
        __syncthreads();
    }

    // C/D layout (m89): lane holds D[m=(lane>>4)*4+r][n=lane&15]
    const int orow = m0 + wm + (fq << 2);
    const int ocol = n0 + wn + fr;
#pragma unroll
    for (int mi = 0; mi < 4; ++mi)
#pragma unroll
        for (int ni = 0; ni < 4; ++ni) {
            u16* yp = Y + (long)(orow + mi * 16) * 5120 + (ocol + ni * 16);
#pragma unroll
            for (int r = 0; r < 4; ++r)
                yp[(long)r * 5120] = f2b(acc[mi][ni][r]);
        }
}

// ---------------- elementwise epilogue (bf16 Y in, f32 outputs) ----------------
__global__ __launch_bounds__(256) void srulstm_epilogue(
    const u16* __restrict__ Y, const float* __restrict__ c_prev,
    const float* __restrict__ bi, const float* __restrict__ bfv,
    const float* __restrict__ bo, const float* __restrict__ bxs,
    const float* __restrict__ bxg, const float* __restrict__ bhg,
    float* __restrict__ out)
{
    const int gid = blockIdx.x * 256 + threadIdx.x;
    const int b = gid >> 8;
    const int j = (gid & 255) << 2;
    const long yb = (long)b * 5120 + j;

    f32x4 zi = loadY4(Y + yb);
    f32x4 zf = loadY4(Y + yb + 1024);
    f32x4 zo = loadY4(Y + yb + 2048);
    f32x4 zc = loadY4(Y + yb + 3072);
    f32x4 zs = loadY4(Y + yb + 4096);

    f32x4 cp  = *(const f32x4*)(c_prev + (long)b * 1024 + j);
    f32x4 vbi = *(const f32x4*)(bi + j);
    f32x4 vbf = *(const f32x4*)(bfv + j);
    f32x4 vbo = *(const f32x4*)(bo + j);
    f32x4 vbs = *(const f32x4*)(bxs + j);
    f32x4 vbg = *(const f32x4*)(bxg + j);
    f32x4 vbh = *(const f32x4*)(bhg + j);

    f32x4 ho, co;
#pragma unroll
    for (int r = 0; r < 4; ++r) {
        float i_t = 1.f / (1.f + __expf(-(zi[r] + vbi[r])));
        float f_t = 1.f / (1.f + __expf(-(zf[r] + vbf[r])));
        float o_t = 1.f / (1.f + __expf(-(zo[r] + vbo[r])));
        float s_t = zs[r] + vbs[r];
        float cand = zc[r] + vbg[r] + vbh[r];
        float g_t = tanhf(s_t * cand);
        float c_t = f_t * cp[r] + i_t * g_t;
        float h_t = o_t * tanhf(c_t);
        ho[r] = h_t;
        co[r] = c_t;
    }
    *(f32x4*)(out + (long)b * 1024 + j) = ho;                 // h_t  [f32]
    *(f32x4*)(out + 4194304L + (long)b * 1024 + j) = co;      // c_t  [f32]
}

extern "C" void kernel_launch(void* const* d_in, const int* in_sizes, int n_in,
                              void* d_out, int out_size, void* d_ws, size_t ws_size,
                              hipStream_t stream)
{
    u16* blob = (u16*)d_ws;
    u16* Y = blob + BLOB_EL;           // bf16 Y: 4096*5120*2 = 41.9 MB; total ws use 77.6 MB
    float* out = (float*)d_out;

    dim3 gg(40, 32), gb(256);
    dim3 eg(4096), eb(256);
    const long convBlocks = BLOB_EL / 8 / 256;               // 8704

    convert_all<<<dim3(convBlocks), dim3(256), 0, stream>>>(
        (const float*)d_in[0], (const float*)d_in[1], (const float*)d_in[3],
        (const float*)d_in[5], (const float*)d_in[7], (const float*)d_in[9],
        (const float*)d_in[11], (const float*)d_in[13], blob);

    srulstm_gemm<<<gg, gb, 0, stream>>>(blob, Y);

    srulstm_epilogue<<<eg, eb, 0, stream>>>(
        Y, (const float*)d_in[2], (const float*)d_in[4], (const float*)d_in[6],
        (const float*)d_in[8], (const float*)d_in[10], (const float*)d_in[12],
        (const float*)d_in[14], out);
}

// Round 6
// 227.294 us; speedup vs baseline: 1.4043x; 1.0931x over previous
//
#include <hip/hip_runtime.h>

typedef unsigned short u16;
typedef __attribute__((ext_vector_type(8))) __bf16 bf16x8;
typedef __attribute__((ext_vector_type(4))) float f32x4;
typedef __attribute__((ext_vector_type(4))) unsigned short u16x4;

#define AS1 __attribute__((address_space(1)))
#define AS3 __attribute__((address_space(3)))

// blob layout (u16 element offsets) -- bf16 copies of GEMM inputs
#define OB_X    0L
#define OB_H    4194304L
#define OB_WI   8388608L
#define OB_WF   10485760L
#define OB_WO   12582912L
#define OB_WXS  14680064L
#define OB_WXG  15728640L
#define OB_WHG  16777216L
#define BLOB_EL 17825792L

__device__ __forceinline__ u16 f2b(float f) {
    unsigned u = __float_as_uint(f);
    u += 0x7fffu + ((u >> 16) & 1u);   // round-to-nearest-even
    return (u16)(u >> 16);
}

// ---------------- f32 -> bf16 blob build (dtypes verified r3-r5) ----------------
__global__ __launch_bounds__(256) void convert_all(
    const float* __restrict__ x, const float* __restrict__ h,
    const float* __restrict__ Wi, const float* __restrict__ Wf,
    const float* __restrict__ Wo, const float* __restrict__ Wxs,
    const float* __restrict__ Wxg, const float* __restrict__ Whg,
    u16* __restrict__ blob)
{
    long e = ((long)blockIdx.x * 256 + threadIdx.x) * 8;
    const float* src; long off;
    if      (e < OB_H)   { src = x;   off = e; }
    else if (e < OB_WI)  { src = h;   off = e - OB_H; }
    else if (e < OB_WF)  { src = Wi;  off = e - OB_WI; }
    else if (e < OB_WO)  { src = Wf;  off = e - OB_WF; }
    else if (e < OB_WXS) { src = Wo;  off = e - OB_WO; }
    else if (e < OB_WXG) { src = Wxs; off = e - OB_WXS; }
    else if (e < OB_WHG) { src = Wxg; off = e - OB_WXG; }
    else                 { src = Whg; off = e - OB_WHG; }
    f32x4 v0 = *(const f32x4*)(src + off);
    f32x4 v1 = *(const f32x4*)(src + off + 4);
    u16x4 o0, o1;
    o0.x = f2b(v0.x); o0.y = f2b(v0.y); o0.z = f2b(v0.z); o0.w = f2b(v0.w);
    o1.x = f2b(v1.x); o1.y = f2b(v1.y); o1.z = f2b(v1.z); o1.w = f2b(v1.w);
    *(u16x4*)(blob + e) = o0;
    *(u16x4*)(blob + e + 4) = o1;
}

__device__ __forceinline__ void stageB(u16* dst, const u16* src, int ld,
                                       int t, int er, int gsw) {
#pragma unroll
    for (int it = 0; it < 2; ++it) {
        const int row = it * 32 + er;
        __builtin_amdgcn_global_load_lds(
            (AS1 void*)(src + row * ld + gsw),
            (AS3 void*)(dst + (it * 256 + t) * 8), 16, 0, 0);
    }
}

__device__ __forceinline__ float sigf(float z) {
    return 1.f / (1.f + __expf(-z));
}

// ---------------- fully-fused SRU-LSTM cell ----------------
// Block = 128 m-rows x 64 j-cols, ALL 5 gate segments (i,f,o,cand,s):
// per K-iter stage one A-tile (128x64) + five B-tiles (64x64 each), 5x MFMA
// per staged A-byte vs the r5 split-N GEMM (barrier amortization 2.9x better).
// Seg accumulators share (row,col) per (lane,reg) -> LSTM epilogue runs in
// fragment registers; h_t/c_t written directly (no Y workspace, no 2nd kernel).
// XOR-swizzled LDS (r4: conflicts 2.8e7 -> 0) on both A and B tiles.
__global__ __launch_bounds__(256, 2) void srulstm_fused(
    const u16* __restrict__ blob,
    const float* __restrict__ c_prev,
    const float* __restrict__ bi, const float* __restrict__ bfv,
    const float* __restrict__ bo, const float* __restrict__ bxs,
    const float* __restrict__ bxg, const float* __restrict__ bhg,
    float* __restrict__ out)
{
    __shared__ __align__(16) u16 As[128 * 64];       // 16 KB
    __shared__ __align__(16) u16 Bs[5 * 64 * 64];    // 40 KB

    const u16* x   = blob + OB_X;
    const u16* h   = blob + OB_H;

    const int t = threadIdx.x;
    const int j0 = blockIdx.x * 64;    // 16 j-slices
    const int m0 = blockIdx.y * 128;   // 32 m-tiles

    // weight row-block bases (rows j0..j0+63)
    const u16* w0   = blob + OB_WI  + j0 * 2048;
    const u16* w1   = blob + OB_WF  + j0 * 2048;
    const u16* w2   = blob + OB_WO  + j0 * 2048;
    const u16* w3lo = blob + OB_WXG + j0 * 1024;
    const u16* w3hi = blob + OB_WHG + j0 * 1024;
    const u16* w4   = blob + OB_WXS + j0 * 1024;

    const u16* aLo = x + m0 * 1024;
    const u16* aHi = h + m0 * 1024;

    const int lane = t & 63;
    const int wave = t >> 6;
    const int wm = (wave >> 1) << 6;   // 0 / 64
    const int wn = (wave & 1) << 5;    // 0 / 32
    const int fr = lane & 15;
    const int fq = lane >> 4;
    const int r7 = fr & 7;             // swizzle key for fragment reads

    f32x4 acc[5][4][2] = {};           // [seg][mi][ni]

    const int er = t >> 3;             // staging row within 32-row chunk
    const int gsw = (((t & 7) ^ (er & 7)) << 3);   // swizzled source granule

    for (int k0 = 0; k0 < 2048; k0 += 64) {
        const u16* aSrc = ((k0 < 1024) ? aLo : aHi) + (k0 & 1023);
#pragma unroll
        for (int it = 0; it < 4; ++it) {
            const int row = it * 32 + er;
            __builtin_amdgcn_global_load_lds(
                (AS1 void*)(aSrc + row * 1024 + gsw),
                (AS3 void*)(As + (it * 256 + t) * 8), 16, 0, 0);
        }
        stageB(Bs,         w0 + k0, 2048, t, er, gsw);
        stageB(Bs + 4096,  w1 + k0, 2048, t, er, gsw);
        stageB(Bs + 8192,  w2 + k0, 2048, t, er, gsw);
        stageB(Bs + 12288, (k0 < 1024) ? (w3lo + k0) : (w3hi + (k0 - 1024)),
               1024, t, er, gsw);
        if (k0 < 1024)
            stageB(Bs + 16384, w4 + k0, 1024, t, er, gsw);
        __syncthreads();
#pragma unroll
        for (int kk = 0; kk < 64; kk += 32) {
            const int sw = ((((kk >> 3) + fq) ^ r7) << 3);
            bf16x8 a[4];
#pragma unroll
            for (int mi = 0; mi < 4; ++mi)
                a[mi] = *(const bf16x8*)(As + (wm + mi * 16 + fr) * 64 + sw);
#pragma unroll
            for (int s = 0; s < 4; ++s) {
                bf16x8 b0 = *(const bf16x8*)(Bs + s * 4096 + (wn + fr) * 64 + sw);
                bf16x8 b1 = *(const bf16x8*)(Bs + s * 4096 + (wn + 16 + fr) * 64 + sw);
#pragma unroll
                for (int mi = 0; mi < 4; ++mi) {
                    acc[s][mi][0] = __builtin_amdgcn_mfma_f32_16x16x32_bf16(
                        a[mi], b0, acc[s][mi][0], 0, 0, 0);
                    acc[s][mi][1] = __builtin_amdgcn_mfma_f32_16x16x32_bf16(
                        a[mi], b1, acc[s][mi][1], 0, 0, 0);
                }
            }
            if (k0 < 1024) {           // seg 4 (Wxs) has K=1024
                bf16x8 b0 = *(const bf16x8*)(Bs + 16384 + (wn + fr) * 64 + sw);
                bf16x8 b1 = *(const bf16x8*)(Bs + 16384 + (wn + 16 + fr) * 64 + sw);
#pragma unroll
                for (int mi = 0; mi < 4; ++mi) {
                    acc[4][mi][0] = __builtin_amdgcn_mfma_f32_16x16x32_bf16(
                        a[mi], b0, acc[4][mi][0], 0, 0, 0);
                    acc[4][mi][1] = __builtin_amdgcn_mfma_f32_16x16x32_bf16(
                        a[mi], b1, acc[4][mi][1], 0, 0, 0);
                }
            }
        }
        __syncthreads();
    }

    // ---- in-register LSTM epilogue ----
    // C/D layout (m89): lane holds D[m=fq*4+r][n=fr]; all 5 segs aligned.
    const int orow = m0 + wm + (fq << 2);
    const int ocol = j0 + wn + fr;
#pragma unroll
    for (int ni = 0; ni < 2; ++ni) {
        const int col = ocol + ni * 16;
        const float bi_v = bi[col],  bf_v = bfv[col], bo_v = bo[col];
        const float bs_v = bxs[col], bg_v = bxg[col], bh_v = bhg[col];
#pragma unroll
        for (int mi = 0; mi < 4; ++mi) {
#pragma unroll
            for (int r = 0; r < 4; ++r) {
                const long idx = (long)(orow + mi * 16 + r) * 1024 + col;
                const float cp = c_prev[idx];
                const float i_t = sigf(acc[0][mi][ni][r] + bi_v);
                const float f_t = sigf(acc[1][mi][ni][r] + bf_v);
                const float o_t = sigf(acc[2][mi][ni][r] + bo_v);
                const float cand = acc[3][mi][ni][r] + bg_v + bh_v;
                const float s_t  = acc[4][mi][ni][r] + bs_v;
                const float g_t = tanhf(s_t * cand);
                const float c_t = f_t * cp + i_t * g_t;
                const float h_t = o_t * tanhf(c_t);
                out[idx] = h_t;                    // h_t
                out[4194304L + idx] = c_t;         // c_t
            }
        }
    }
}

extern "C" void kernel_launch(void* const* d_in, const int* in_sizes, int n_in,
                              void* d_out, int out_size, void* d_ws, size_t ws_size,
                              hipStream_t stream)
{
    u16* blob = (u16*)d_ws;            // 35.7 MB
    float* out = (float*)d_out;

    const long convBlocks = BLOB_EL / 8 / 256;     // 8704

    convert_all<<<dim3(convBlocks), dim3(256), 0, stream>>>(
        (const float*)d_in[0], (const float*)d_in[1], (const float*)d_in[3],
        (const float*)d_in[5], (const float*)d_in[7], (const float*)d_in[9],
        (const float*)d_in[11], (const float*)d_in[13], blob);

    srulstm_fused<<<dim3(16, 32), dim3(256), 0, stream>>>(
        blob, (const float*)d_in[2], (const float*)d_in[4], (const float*)d_in[6],
        (const float*)d_in[8], (const float*)d_in[10], (const float*)d_in[12],
        (const float*)d_in[14], out);
}